// Round 9
// baseline (432.022 us; speedup 1.0000x reference)
//
#include <hip/hip_runtime.h>
#include <hip/hip_bf16.h>
#include <stdint.h>

typedef __attribute__((ext_vector_type(8))) __bf16 bf16x8;
typedef __attribute__((ext_vector_type(4))) float f32x4;
typedef __attribute__((ext_vector_type(4))) unsigned int u32x4;
typedef __attribute__((ext_vector_type(4))) unsigned short u16x4;

__device__ __forceinline__ unsigned short f2bf(float f) {
  union { float f; unsigned int u; } v; v.f = f;
  unsigned int r = v.u + 0x7fffu + ((v.u >> 16) & 1u);
  return (unsigned short)(r >> 16);
}

// async global->LDS, 16B per lane. LDS dest = wave-uniform base + lane*16.
__device__ __forceinline__ void gload_lds16(const void* g, void* l) {
  __builtin_amdgcn_global_load_lds(
      (const __attribute__((address_space(1))) unsigned int*)g,
      (__attribute__((address_space(3))) unsigned int*)l, 16, 0, 0);
}

// ---------------- fp32 -> bf16 cast (vectorized) ----------------
__global__ __launch_bounds__(256) void cast_f32_bf16(const float* __restrict__ in,
                                                     unsigned short* __restrict__ out,
                                                     int n) {
  int i = (blockIdx.x * 256 + threadIdx.x) * 4;
  if (i >= n) return;
  f32x4 v = *(const f32x4*)&in[i];
  u16x4 o;
  o[0] = f2bf(v[0]); o[1] = f2bf(v[1]); o[2] = f2bf(v[2]); o[3] = f2bf(v[3]);
  *(u16x4*)&out[i] = o;
}

// ---------------- fp32 add (split-K reduce) ----------------
__global__ __launch_bounds__(256) void addf32(float* __restrict__ out,
                                              const float* __restrict__ part, int n) {
  int i = (blockIdx.x * 256 + threadIdx.x) * 4;
  if (i >= n) return;
  f32x4 a = *(const f32x4*)&out[i];
  f32x4 b = *(const f32x4*)&part[i];
  a[0] += b[0]; a[1] += b[1]; a[2] += b[2]; a[3] += b[3];
  *(f32x4*)&out[i] = a;
}

// ---------------- bf16 GEMM: C[M,N] = A[M,K] * B[N,K]^T ----------------
// 128x128 tile, BK=32, 4 waves, double-buffered global_load_lds w=16.
// blockIdx.z selects a K-slice of length KS (split-K); z=0 -> Cv, z>0 -> Cp.
template<int OUT_BF16>
__global__ __launch_bounds__(256) void gemm_bt(const unsigned short* __restrict__ A,
                                               const unsigned short* __restrict__ B,
                                               void* __restrict__ Cv,
                                               float* __restrict__ Cp,
                                               int M, int N, int K, int KS) {
  __shared__ unsigned short As[2][128 * 32];
  __shared__ unsigned short Bs[2][128 * 32];

  const int tid  = threadIdx.x;
  const int lane = tid & 63;
  const int wave = tid >> 6;            // 0..3
  const int wr = (wave >> 1) * 64;
  const int wc = (wave & 1) * 64;
  const int row0 = blockIdx.y * 128;
  const int col0 = blockIdx.x * 128;
  const int l16 = lane & 15;
  const int lk  = (lane >> 4) * 8;
  const int kbeg = blockIdx.z * KS;

  // staging: instr t (= wave*2+i) covers LDS rows t*16..t*16+15.
  const int srow = lane >> 2;
  const int sc   = (lane & 3) * 8;

  f32x4 acc[4][4] = {};

  // prologue: fill buffer 0
#pragma unroll
  for (int i = 0; i < 2; ++i) {
    int t = wave * 2 + i;
    int r = t * 16 + srow;
    gload_lds16(&A[(size_t)(row0 + r) * K + kbeg + sc], &As[0][t * 512]);
    gload_lds16(&B[(size_t)(col0 + r) * K + kbeg + sc], &Bs[0][t * 512]);
  }
  __syncthreads();

  int cur = 0;
  for (int k0 = kbeg; k0 < kbeg + KS; k0 += 32, cur ^= 1) {
    if (k0 + 32 < kbeg + KS) {
#pragma unroll
      for (int i = 0; i < 2; ++i) {
        int t = wave * 2 + i;
        int r = t * 16 + srow;
        gload_lds16(&A[(size_t)(row0 + r) * K + k0 + 32 + sc], &As[cur ^ 1][t * 512]);
        gload_lds16(&B[(size_t)(col0 + r) * K + k0 + 32 + sc], &Bs[cur ^ 1][t * 512]);
      }
    }

    bf16x8 af[4], bfr[4];
#pragma unroll
    for (int i = 0; i < 4; ++i) af[i]  = *(const bf16x8*)&As[cur][(wr + i * 16 + l16) * 32 + lk];
#pragma unroll
    for (int i = 0; i < 4; ++i) bfr[i] = *(const bf16x8*)&Bs[cur][(wc + i * 16 + l16) * 32 + lk];
#pragma unroll
    for (int i = 0; i < 4; ++i)
#pragma unroll
      for (int j = 0; j < 4; ++j)
        acc[i][j] = __builtin_amdgcn_mfma_f32_16x16x32_bf16(af[i], bfr[j], acc[i][j], 0, 0, 0);

    __syncthreads();
  }

  void* outp = (blockIdx.z == 0) ? Cv : (void*)Cp;

  // epilogue: C/D layout col = lane&15, row = (lane>>4)*4 + r
  const int orow = (lane >> 4) * 4;
#pragma unroll
  for (int i = 0; i < 4; ++i)
#pragma unroll
    for (int j = 0; j < 4; ++j)
#pragma unroll
      for (int r = 0; r < 4; ++r) {
        size_t gr = row0 + wr + i * 16 + orow + r;
        size_t gc = col0 + wc + j * 16 + l16;
        float v = acc[i][j][r];
        if (OUT_BF16) ((unsigned short*)outp)[gr * N + gc] = f2bf(v);
        else          ((float*)outp)[gr * N + gc] = v;
      }
}

// ---------------- causal flash attention ----------------
// qkv: [2048][6144] bf16 rows = [q | k | v], head h uses cols h*128..+127
// One block: 64 q-rows of one head; 4 waves x 16 q-rows.
// K is read straight from cache (16 KB tile, L1-resident; no LDS staging).
// V^T double-buffered in LDS -> ONE barrier per kv-iter.
// Softmax: lane-local partial sums (reduced once at end) + defer-max (T13).
#define VT_IDX(c, t) ((((c) * 64) + (t)) ^ (((((c) ^ ((c) >> 3))) & 7) << 3))
#define PS_IDX(q, c) ((((q) * 64) + (c)) ^ (((q) & 7) << 3))

__global__ __launch_bounds__(256, 4) void attn_kernel(const unsigned short* __restrict__ qkv,
                                                      unsigned short* __restrict__ ctx) {
  __shared__ unsigned short VTs[2][128 * 64];  // V^T [c][kv], swizzled, dbuf
  __shared__ unsigned short Ps[4][16 * 64];    // per-wave P [q][kv], swizzled

  const int tid  = threadIdx.x;
  const int lane = tid & 63;
  const int w    = tid >> 6;
  const int l16  = lane & 15;
  const int lk8  = (lane >> 4) * 8;

  // balanced (h, qb): co-resident blocks (flat, flat+256) have complementary qb.
  const int flat = blockIdx.x + blockIdx.y * 32;
  int h, qb;
  if (flat < 256) { h = flat >> 5; qb = flat & 31; }
  else            { int f2 = flat - 256; h = 8 + (f2 >> 5); qb = 31 - (f2 & 31); }

  const int qrow = qb * 64 + w * 16;

  const unsigned short* Kbase = qkv + 2048 + h * 128;
  const unsigned short* Vbase = qkv + 4096 + h * 128;

  // Q fragments in registers for the whole kv loop
  bf16x8 qf[4];
#pragma unroll
  for (int kk = 0; kk < 4; ++kk)
    qf[kk] = *(const bf16x8*)&qkv[(size_t)(qrow + l16) * 6144 + h * 128 + kk * 32 + lk8];

  f32x4 o[8] = {};
  float m[4], ls[4];
#pragma unroll
  for (int r = 0; r < 4; ++r) { m[r] = -1e30f; ls[r] = 0.f; }

  const float sscale = 0.08838834764831845f * 1.4426950408889634f;  // 1/sqrt(128)*log2e
  const int qg0 = qrow + (lane >> 4) * 4;

  // V^T staging: thread owns kv rows t0v..t0v+3, channels c0v..c0v+7
  const int t0v = (tid & 15) * 4;
  const int c0v = (tid >> 4) * 8;

  // prologue: V tile 0 -> VTs[0] (visible after iter-0 barrier)
  {
    u32x4 vr[4];
#pragma unroll
    for (int r = 0; r < 4; ++r)
      vr[r] = *(const u32x4*)&Vbase[(size_t)(t0v + r) * 6144 + c0v];
    const unsigned short* p0 = (const unsigned short*)&vr[0];
    const unsigned short* p1 = (const unsigned short*)&vr[1];
    const unsigned short* p2 = (const unsigned short*)&vr[2];
    const unsigned short* p3 = (const unsigned short*)&vr[3];
#pragma unroll
    for (int j = 0; j < 8; ++j) {
      u16x4 wv; wv[0] = p0[j]; wv[1] = p1[j]; wv[2] = p2[j]; wv[3] = p3[j];
      *(u16x4*)&VTs[0][VT_IDX(c0v + j, t0v)] = wv;
    }
  }

  const int nkb = qb + 1;
  for (int kb = 0; kb < nkb; ++kb) {
    const int cur = kb & 1;
    const bool pre = (kb + 1 < nkb);

    // prefetch next V tile to regs BEFORE the barrier (HBM latency overlap)
    u32x4 vr[4];
    if (pre) {
#pragma unroll
      for (int r = 0; r < 4; ++r)
        vr[r] = *(const u32x4*)&Vbase[(size_t)((kb + 1) * 64 + t0v + r) * 6144 + c0v];
    }

    __syncthreads();  // prev iter's PV reads of VTs[cur^1] done; VTs[cur] writes visible

    if (pre) {
      const unsigned short* p0 = (const unsigned short*)&vr[0];
      const unsigned short* p1 = (const unsigned short*)&vr[1];
      const unsigned short* p2 = (const unsigned short*)&vr[2];
      const unsigned short* p3 = (const unsigned short*)&vr[3];
#pragma unroll
      for (int j = 0; j < 8; ++j) {
        u16x4 wv; wv[0] = p0[j]; wv[1] = p1[j]; wv[2] = p2[j]; wv[3] = p3[j];
        *(u16x4*)&VTs[cur ^ 1][VT_IDX(c0v + j, t0v)] = wv;
      }
    }

    // S = Q K^T, K fragments straight from global (L1-resident tile)
    f32x4 s[4] = {};
#pragma unroll
    for (int n = 0; n < 4; ++n) {
      const unsigned short* krow = &Kbase[(size_t)(kb * 64 + n * 16 + l16) * 6144];
#pragma unroll
      for (int kk = 0; kk < 4; ++kk) {
        bf16x8 kf = *(const bf16x8*)&krow[kk * 32 + lk8];
        s[n] = __builtin_amdgcn_mfma_f32_16x16x32_bf16(qf[kk], kf, s[n], 0, 0, 0);
      }
    }

    // scale + causal mask + lane-local max
    const bool diag = (kb == qb);
    float pmax[4];
#pragma unroll
    for (int r = 0; r < 4; ++r) pmax[r] = -1e30f;
#pragma unroll
    for (int n = 0; n < 4; ++n) {
      int kg = kb * 64 + n * 16 + l16;
#pragma unroll
      for (int r = 0; r < 4; ++r) {
        float v = s[n][r] * sscale;
        if (diag && kg > qg0 + r) v = -1e30f;
        s[n][r] = v;
        pmax[r] = fmaxf(pmax[r], v);
      }
    }

    // defer-max: only reduce+rescale when some row grew past m+8
    bool need = (pmax[0] > m[0] + 8.f) | (pmax[1] > m[1] + 8.f) |
                (pmax[2] > m[2] + 8.f) | (pmax[3] > m[3] + 8.f);
    if (__ballot(need)) {
#pragma unroll
      for (int d = 1; d < 16; d <<= 1)
#pragma unroll
        for (int r = 0; r < 4; ++r) pmax[r] = fmaxf(pmax[r], __shfl_xor(pmax[r], d));
#pragma unroll
      for (int r = 0; r < 4; ++r) {
        float mn = fmaxf(m[r], pmax[r]);
        float alpha = exp2f(m[r] - mn);
        m[r] = mn;
        ls[r] *= alpha;
#pragma unroll
        for (int n = 0; n < 8; ++n) o[n][r] *= alpha;
      }
    }

    // P = exp2(s - m): write bf16 to Ps, accumulate lane-local denominator
#pragma unroll
    for (int n = 0; n < 4; ++n)
#pragma unroll
      for (int r = 0; r < 4; ++r) {
        float p = exp2f(s[n][r] - m[r]);
        ls[r] += p;
        Ps[w][PS_IDX((lane >> 4) * 4 + r, n * 16 + l16)] = f2bf(p);
      }
    asm volatile("s_waitcnt lgkmcnt(0)" ::: "memory");  // wave-private Ps: no barrier

    // O += P V
#pragma unroll
    for (int kk = 0; kk < 2; ++kk) {
      bf16x8 pf = *(const bf16x8*)&Ps[w][PS_IDX(l16, kk * 32 + lk8)];
#pragma unroll
      for (int n = 0; n < 8; ++n) {
        bf16x8 vf = *(const bf16x8*)&VTs[cur][VT_IDX(n * 16 + l16, kk * 32 + lk8)];
        o[n] = __builtin_amdgcn_mfma_f32_16x16x32_bf16(pf, vf, o[n], 0, 0, 0);
      }
    }
  }

  // denominator: one cross-lane reduce at the end
#pragma unroll
  for (int d = 1; d < 16; d <<= 1)
#pragma unroll
    for (int r = 0; r < 4; ++r) ls[r] += __shfl_xor(ls[r], d);

  // epilogue
#pragma unroll
  for (int r = 0; r < 4; ++r) {
    float inv = 1.0f / ls[r];
    size_t gr = qrow + (lane >> 4) * 4 + r;
#pragma unroll
    for (int n = 0; n < 8; ++n)
      ctx[gr * 2048 + h * 128 + n * 16 + l16] = f2bf(o[n][r] * inv);
  }
}

// ---------------- launch ----------------
extern "C" void kernel_launch(void* const* d_in, const int* in_sizes, int n_in,
                              void* d_out, int out_size, void* d_ws, size_t ws_size,
                              hipStream_t stream) {
  const float* x  = (const float*)d_in[0];
  const float* Wa = (const float*)d_in[1];
  const float* Wp = (const float*)d_in[2];
  float* out = (float*)d_out;

  char* ws = (char*)d_ws;
  unsigned short* xb   = (unsigned short*)(ws);                       // 8 MB
  unsigned short* wab  = (unsigned short*)(ws + 8388608);             // 24 MB
  unsigned short* wpb  = (unsigned short*)(ws + 33554432);            // 8 MB
  unsigned short* qkvb = (unsigned short*)(ws + 41943040);            // 24 MB
  unsigned short* ctx  = (unsigned short*)(ws + 67108864);            // 8 MB
  float* proj_part     = (float*)(ws + 75497472);                     // 16 MB (optional)
  const bool splitk = ws_size >= (size_t)(75497472 + 16777216);

  cast_f32_bf16<<<4096, 256, 0, stream>>>(x, xb, 2048 * 2048);
  cast_f32_bf16<<<12288, 256, 0, stream>>>(Wa, wab, 6144 * 2048);
  cast_f32_bf16<<<4096, 256, 0, stream>>>(Wp, wpb, 2048 * 2048);

  // qkv = x @ W_attn^T : [2048, 6144]
  gemm_bt<1><<<dim3(48, 16, 1), 256, 0, stream>>>(xb, wab, qkvb, nullptr,
                                                  2048, 6144, 2048, 2048);

  // causal multi-head attention -> ctx [2048, 2048] bf16
  attn_kernel<<<dim3(32, 16), 256, 0, stream>>>(qkvb, ctx);

  // out = ctx @ W_proj^T : [2048, 2048] fp32 (split-K=2 when ws allows)
  if (splitk) {
    gemm_bt<0><<<dim3(16, 16, 2), 256, 0, stream>>>(ctx, wpb, out, proj_part,
                                                    2048, 2048, 2048, 1024);
    addf32<<<4096, 256, 0, stream>>>(out, proj_part, 2048 * 2048);
  } else {
    gemm_bt<0><<<dim3(16, 16, 1), 256, 0, stream>>>(ctx, wpb, out, nullptr,
                                                    2048, 2048, 2048, 2048);
  }
}

// Round 12
// 278.452 us; speedup vs baseline: 1.5515x; 1.5515x over previous
//
#include <hip/hip_runtime.h>
#include <hip/hip_bf16.h>
#include <stdint.h>

typedef __attribute__((ext_vector_type(8))) __bf16 bf16x8;
typedef __attribute__((ext_vector_type(4))) float f32x4;
typedef __attribute__((ext_vector_type(4))) unsigned int u32x4;
typedef __attribute__((ext_vector_type(4))) unsigned short u16x4;

__device__ __forceinline__ unsigned short f2bf(float f) {
  union { float f; unsigned int u; } v; v.f = f;
  unsigned int r = v.u + 0x7fffu + ((v.u >> 16) & 1u);
  return (unsigned short)(r >> 16);
}

// async global->LDS, 16B per lane. LDS dest = wave-uniform base + lane*16.
__device__ __forceinline__ void gload_lds16(const void* g, void* l) {
  __builtin_amdgcn_global_load_lds(
      (const __attribute__((address_space(1))) unsigned int*)g,
      (__attribute__((address_space(3))) unsigned int*)l, 16, 0, 0);
}

// ---------------- fp32 -> bf16 cast (vectorized) ----------------
__global__ __launch_bounds__(256) void cast_f32_bf16(const float* __restrict__ in,
                                                     unsigned short* __restrict__ out,
                                                     int n) {
  int i = (blockIdx.x * 256 + threadIdx.x) * 4;
  if (i >= n) return;
  f32x4 v = *(const f32x4*)&in[i];
  u16x4 o;
  o[0] = f2bf(v[0]); o[1] = f2bf(v[1]); o[2] = f2bf(v[2]); o[3] = f2bf(v[3]);
  *(u16x4*)&out[i] = o;
}

// ---------------- fp32 add (split-K reduce) ----------------
__global__ __launch_bounds__(256) void addf32(float* __restrict__ out,
                                              const float* __restrict__ part, int n) {
  int i = (blockIdx.x * 256 + threadIdx.x) * 4;
  if (i >= n) return;
  f32x4 a = *(const f32x4*)&out[i];
  f32x4 b = *(const f32x4*)&part[i];
  a[0] += b[0]; a[1] += b[1]; a[2] += b[2]; a[3] += b[3];
  *(f32x4*)&out[i] = a;
}

// ---------------- bf16 GEMM: C[M,N] = A[M,K] * B[N,K]^T ----------------
// 128x128 tile, BK=32, 4 waves, double-buffered global_load_lds w=16.
// blockIdx.z selects a K-slice of length KS (split-K); z=0 -> Cv, z>0 -> Cp.
template<int OUT_BF16>
__global__ __launch_bounds__(256) void gemm_bt(const unsigned short* __restrict__ A,
                                               const unsigned short* __restrict__ B,
                                               void* __restrict__ Cv,
                                               float* __restrict__ Cp,
                                               int M, int N, int K, int KS) {
  __shared__ unsigned short As[2][128 * 32];
  __shared__ unsigned short Bs[2][128 * 32];

  const int tid  = threadIdx.x;
  const int lane = tid & 63;
  const int wave = tid >> 6;            // 0..3
  const int wr = (wave >> 1) * 64;
  const int wc = (wave & 1) * 64;
  const int row0 = blockIdx.y * 128;
  const int col0 = blockIdx.x * 128;
  const int l16 = lane & 15;
  const int lk  = (lane >> 4) * 8;
  const int kbeg = blockIdx.z * KS;

  // staging: instr t (= wave*2+i) covers LDS rows t*16..t*16+15.
  const int srow = lane >> 2;
  const int sc   = (lane & 3) * 8;

  f32x4 acc[4][4] = {};

  // prologue: fill buffer 0
#pragma unroll
  for (int i = 0; i < 2; ++i) {
    int t = wave * 2 + i;
    int r = t * 16 + srow;
    gload_lds16(&A[(size_t)(row0 + r) * K + kbeg + sc], &As[0][t * 512]);
    gload_lds16(&B[(size_t)(col0 + r) * K + kbeg + sc], &Bs[0][t * 512]);
  }
  __syncthreads();

  int cur = 0;
  for (int k0 = kbeg; k0 < kbeg + KS; k0 += 32, cur ^= 1) {
    if (k0 + 32 < kbeg + KS) {
#pragma unroll
      for (int i = 0; i < 2; ++i) {
        int t = wave * 2 + i;
        int r = t * 16 + srow;
        gload_lds16(&A[(size_t)(row0 + r) * K + k0 + 32 + sc], &As[cur ^ 1][t * 512]);
        gload_lds16(&B[(size_t)(col0 + r) * K + k0 + 32 + sc], &Bs[cur ^ 1][t * 512]);
      }
    }

    bf16x8 af[4], bfr[4];
#pragma unroll
    for (int i = 0; i < 4; ++i) af[i]  = *(const bf16x8*)&As[cur][(wr + i * 16 + l16) * 32 + lk];
#pragma unroll
    for (int i = 0; i < 4; ++i) bfr[i] = *(const bf16x8*)&Bs[cur][(wc + i * 16 + l16) * 32 + lk];
#pragma unroll
    for (int i = 0; i < 4; ++i)
#pragma unroll
      for (int j = 0; j < 4; ++j)
        acc[i][j] = __builtin_amdgcn_mfma_f32_16x16x32_bf16(af[i], bfr[j], acc[i][j], 0, 0, 0);

    __syncthreads();
  }

  void* outp = (blockIdx.z == 0) ? Cv : (void*)Cp;

  // epilogue: C/D layout col = lane&15, row = (lane>>4)*4 + r
  const int orow = (lane >> 4) * 4;
#pragma unroll
  for (int i = 0; i < 4; ++i)
#pragma unroll
    for (int j = 0; j < 4; ++j)
#pragma unroll
      for (int r = 0; r < 4; ++r) {
        size_t gr = row0 + wr + i * 16 + orow + r;
        size_t gc = col0 + wc + j * 16 + l16;
        float v = acc[i][j][r];
        if (OUT_BF16) ((unsigned short*)outp)[gr * N + gc] = f2bf(v);
        else          ((float*)outp)[gr * N + gc] = v;
      }
}

// ---------------- causal flash attention ----------------
// qkv: [2048][6144] bf16 rows = [q | k | v], head h uses cols h*128..+127
// One block: 64 q-rows of one head; 4 waves x 16 q-rows.
// K AND V double-buffered in LDS (reg-staged) -> ONE barrier per kv-iter.
// Swizzles chosen so both write and read sides are <=2-way:
//  Ks: rows R..R+3 staged by one wave-group get distinct (r&7) offsets; reads
//      over 16 rows -> 8 offsets (2-way).
//  Ps: write lane-groups have q in {r,r+4,r+8,r+12} -> (q&7)^((q>>2)&3) distinct;
//      reads over q=0..15 -> 2-way.
#define KS_IDX(r, c) ((((r) * 128) + (c)) ^ (((r) & 7) << 3))
#define VT_IDX(c, t) ((((c) * 64) + (t)) ^ (((((c) ^ ((c) >> 3))) & 7) << 3))
#define PS_IDX(q, c) ((((q) * 64) + (c)) ^ (((((q) & 7) ^ (((q) >> 2) & 3))) << 3))

__global__ __launch_bounds__(256, 2) void attn_kernel(const unsigned short* __restrict__ qkv,
                                                      unsigned short* __restrict__ ctx) {
  __shared__ unsigned short Ks[2][64 * 128];   // K [kv][c], swizzled, dbuf
  __shared__ unsigned short VTs[2][128 * 64];  // V^T [c][kv], swizzled, dbuf
  __shared__ unsigned short Ps[4][16 * 64];    // per-wave P [q][kv], swizzled

  const int tid  = threadIdx.x;
  const int lane = tid & 63;
  const int w    = tid >> 6;
  const int l16  = lane & 15;
  const int lk8  = (lane >> 4) * 8;

  // balanced (h, qb): co-resident blocks (flat, flat+256) have complementary qb.
  const int flat = blockIdx.x + blockIdx.y * 32;
  int h, qb;
  if (flat < 256) { h = flat >> 5; qb = flat & 31; }
  else            { int f2 = flat - 256; h = 8 + (f2 >> 5); qb = 31 - (f2 & 31); }

  const int qrow = qb * 64 + w * 16;

  const unsigned short* Kbase = qkv + 2048 + h * 128;
  const unsigned short* Vbase = qkv + 4096 + h * 128;

  // Q fragments in registers for the whole kv loop
  bf16x8 qf[4];
#pragma unroll
  for (int kk = 0; kk < 4; ++kk)
    qf[kk] = *(const bf16x8*)&qkv[(size_t)(qrow + l16) * 6144 + h * 128 + kk * 32 + lk8];

  f32x4 o[8] = {};
  float m[4], ls[4];
#pragma unroll
  for (int r = 0; r < 4; ++r) { m[r] = -1e30f; ls[r] = 0.f; }

  const float sscale = 0.08838834764831845f * 1.4426950408889634f;  // 1/sqrt(128)*log2e
  const int qg0 = qrow + (lane >> 4) * 4;

  // K staging: thread covers rows (it*256+tid)>>4, col ((it*256+tid)&15)*8
  // V^T staging: thread owns kv rows t0v..t0v+3, channels c0v..c0v+7
  const int t0v = (tid & 15) * 4;
  const int c0v = (tid >> 4) * 8;

  // prologue: stage tile 0 into buffers 0 (visible after iter-0 barrier)
  {
    u32x4 kr[4], vr[4];
#pragma unroll
    for (int it = 0; it < 4; ++it) {
      int idx = it * 256 + tid;
      int row = idx >> 4, c0 = (idx & 15) * 8;
      kr[it] = *(const u32x4*)&Kbase[(size_t)row * 6144 + c0];
    }
#pragma unroll
    for (int r = 0; r < 4; ++r)
      vr[r] = *(const u32x4*)&Vbase[(size_t)(t0v + r) * 6144 + c0v];
#pragma unroll
    for (int it = 0; it < 4; ++it) {
      int idx = it * 256 + tid;
      int row = idx >> 4, c0 = (idx & 15) * 8;
      *(u32x4*)&Ks[0][KS_IDX(row, c0)] = kr[it];
    }
    const unsigned short* p0 = (const unsigned short*)&vr[0];
    const unsigned short* p1 = (const unsigned short*)&vr[1];
    const unsigned short* p2 = (const unsigned short*)&vr[2];
    const unsigned short* p3 = (const unsigned short*)&vr[3];
#pragma unroll
    for (int j = 0; j < 8; ++j) {
      u16x4 wv; wv[0] = p0[j]; wv[1] = p1[j]; wv[2] = p2[j]; wv[3] = p3[j];
      *(u16x4*)&VTs[0][VT_IDX(c0v + j, t0v)] = wv;
    }
  }

  const int nkb = qb + 1;
  for (int kb = 0; kb < nkb; ++kb) {
    const int cur = kb & 1;
    const bool pre = (kb + 1 < nkb);

    // prefetch next K/V tile to regs BEFORE the barrier (HBM/L2 latency overlap)
    u32x4 kr[4], vr[4];
    if (pre) {
#pragma unroll
      for (int it = 0; it < 4; ++it) {
        int idx = it * 256 + tid;
        int row = idx >> 4, c0 = (idx & 15) * 8;
        kr[it] = *(const u32x4*)&Kbase[(size_t)((kb + 1) * 64 + row) * 6144 + c0];
      }
#pragma unroll
      for (int r = 0; r < 4; ++r)
        vr[r] = *(const u32x4*)&Vbase[(size_t)((kb + 1) * 64 + t0v + r) * 6144 + c0v];
    }

    // barrier: tile kb writes (prev iter / prologue) visible; prev-iter reads
    // of buffer cur^1 complete -> safe to overwrite with tile kb+1.
    __syncthreads();

    if (pre) {
#pragma unroll
      for (int it = 0; it < 4; ++it) {
        int idx = it * 256 + tid;
        int row = idx >> 4, c0 = (idx & 15) * 8;
        *(u32x4*)&Ks[cur ^ 1][KS_IDX(row, c0)] = kr[it];
      }
      const unsigned short* p0 = (const unsigned short*)&vr[0];
      const unsigned short* p1 = (const unsigned short*)&vr[1];
      const unsigned short* p2 = (const unsigned short*)&vr[2];
      const unsigned short* p3 = (const unsigned short*)&vr[3];
#pragma unroll
      for (int j = 0; j < 8; ++j) {
        u16x4 wv; wv[0] = p0[j]; wv[1] = p1[j]; wv[2] = p2[j]; wv[3] = p3[j];
        *(u16x4*)&VTs[cur ^ 1][VT_IDX(c0v + j, t0v)] = wv;
      }
    }

    // S = Q K^T (16x64 per wave), K from LDS
    f32x4 s[4] = {};
#pragma unroll
    for (int n = 0; n < 4; ++n)
#pragma unroll
      for (int kk = 0; kk < 4; ++kk) {
        bf16x8 kf = *(const bf16x8*)&Ks[cur][KS_IDX(n * 16 + l16, kk * 32 + lk8)];
        s[n] = __builtin_amdgcn_mfma_f32_16x16x32_bf16(qf[kk], kf, s[n], 0, 0, 0);
      }

    // scale + causal mask + lane-local max
    const bool diag = (kb == qb);
    float pmax[4];
#pragma unroll
    for (int r = 0; r < 4; ++r) pmax[r] = -1e30f;
#pragma unroll
    for (int n = 0; n < 4; ++n) {
      int kg = kb * 64 + n * 16 + l16;
#pragma unroll
      for (int r = 0; r < 4; ++r) {
        float v = s[n][r] * sscale;
        if (diag && kg > qg0 + r) v = -1e30f;
        s[n][r] = v;
        pmax[r] = fmaxf(pmax[r], v);
      }
    }

    // defer-max: only reduce+rescale when some row grew past m+8
    bool need = (pmax[0] > m[0] + 8.f) | (pmax[1] > m[1] + 8.f) |
                (pmax[2] > m[2] + 8.f) | (pmax[3] > m[3] + 8.f);
    if (__ballot(need)) {
#pragma unroll
      for (int d = 1; d < 16; d <<= 1)
#pragma unroll
        for (int r = 0; r < 4; ++r) pmax[r] = fmaxf(pmax[r], __shfl_xor(pmax[r], d));
#pragma unroll
      for (int r = 0; r < 4; ++r) {
        float mn = fmaxf(m[r], pmax[r]);
        float alpha = exp2f(m[r] - mn);
        m[r] = mn;
        ls[r] *= alpha;
#pragma unroll
        for (int n = 0; n < 8; ++n) o[n][r] *= alpha;
      }
    }

    // P = exp2(s - m): bf16 to Ps, lane-local denominator accumulation
#pragma unroll
    for (int n = 0; n < 4; ++n)
#pragma unroll
      for (int r = 0; r < 4; ++r) {
        float p = exp2f(s[n][r] - m[r]);
        ls[r] += p;
        Ps[w][PS_IDX((lane >> 4) * 4 + r, n * 16 + l16)] = f2bf(p);
      }
    asm volatile("s_waitcnt lgkmcnt(0)" ::: "memory");  // wave-private Ps: no barrier

    // O += P V
#pragma unroll
    for (int kk = 0; kk < 2; ++kk) {
      bf16x8 pf = *(const bf16x8*)&Ps[w][PS_IDX(l16, kk * 32 + lk8)];
#pragma unroll
      for (int n = 0; n < 8; ++n) {
        bf16x8 vf = *(const bf16x8*)&VTs[cur][VT_IDX(n * 16 + l16, kk * 32 + lk8)];
        o[n] = __builtin_amdgcn_mfma_f32_16x16x32_bf16(pf, vf, o[n], 0, 0, 0);
      }
    }
  }

  // denominator: one cross-lane reduce at the end
#pragma unroll
  for (int d = 1; d < 16; d <<= 1)
#pragma unroll
    for (int r = 0; r < 4; ++r) ls[r] += __shfl_xor(ls[r], d);

  // epilogue
#pragma unroll
  for (int r = 0; r < 4; ++r) {
    float inv = 1.0f / ls[r];
    size_t gr = qrow + (lane >> 4) * 4 + r;
#pragma unroll
    for (int n = 0; n < 8; ++n)
      ctx[gr * 2048 + h * 128 + n * 16 + l16] = f2bf(o[n][r] * inv);
  }
}

// ---------------- launch ----------------
extern "C" void kernel_launch(void* const* d_in, const int* in_sizes, int n_in,
                              void* d_out, int out_size, void* d_ws, size_t ws_size,
                              hipStream_t stream) {
  const float* x  = (const float*)d_in[0];
  const float* Wa = (const float*)d_in[1];
  const float* Wp = (const float*)d_in[2];
  float* out = (float*)d_out;

  char* ws = (char*)d_ws;
  unsigned short* xb   = (unsigned short*)(ws);                       // 8 MB
  unsigned short* wab  = (unsigned short*)(ws + 8388608);             // 24 MB
  unsigned short* wpb  = (unsigned short*)(ws + 33554432);            // 8 MB
  unsigned short* qkvb = (unsigned short*)(ws + 41943040);            // 24 MB
  unsigned short* ctx  = (unsigned short*)(ws + 67108864);            // 8 MB
  float* proj_part     = (float*)(ws + 75497472);                     // 16 MB (optional)
  const bool splitk = ws_size >= (size_t)(75497472 + 16777216);

  cast_f32_bf16<<<4096, 256, 0, stream>>>(x, xb, 2048 * 2048);
  cast_f32_bf16<<<12288, 256, 0, stream>>>(Wa, wab, 6144 * 2048);
  cast_f32_bf16<<<4096, 256, 0, stream>>>(Wp, wpb, 2048 * 2048);

  // qkv = x @ W_attn^T : [2048, 6144]
  gemm_bt<1><<<dim3(48, 16, 1), 256, 0, stream>>>(xb, wab, qkvb, nullptr,
                                                  2048, 6144, 2048, 2048);

  // causal multi-head attention -> ctx [2048, 2048] bf16
  attn_kernel<<<dim3(32, 16), 256, 0, stream>>>(qkvb, ctx);

  // out = ctx @ W_proj^T : [2048, 2048] fp32 (split-K=2 when ws allows)
  if (splitk) {
    gemm_bt<0><<<dim3(16, 16, 2), 256, 0, stream>>>(ctx, wpb, out, proj_part,
                                                    2048, 2048, 2048, 1024);
    addf32<<<4096, 256, 0, stream>>>(out, proj_part, 2048 * 2048);
  } else {
    gemm_bt<0><<<dim3(16, 16, 1), 256, 0, stream>>>(ctx, wpb, out, nullptr,
                                                    2048, 2048, 2048, 2048);
  }
}

// Round 13
// 277.894 us; speedup vs baseline: 1.5546x; 1.0020x over previous
//
#include <hip/hip_runtime.h>
#include <hip/hip_bf16.h>
#include <stdint.h>

typedef __attribute__((ext_vector_type(8))) __bf16 bf16x8;
typedef __attribute__((ext_vector_type(4))) float f32x4;
typedef __attribute__((ext_vector_type(4))) unsigned int u32x4;
typedef __attribute__((ext_vector_type(4))) unsigned short u16x4;

__device__ __forceinline__ unsigned short f2bf(float f) {
  union { float f; unsigned int u; } v; v.f = f;
  unsigned int r = v.u + 0x7fffu + ((v.u >> 16) & 1u);
  return (unsigned short)(r >> 16);
}

// async global->LDS, 16B per lane. LDS dest = wave-uniform base + lane*16.
__device__ __forceinline__ void gload_lds16(const void* g, void* l) {
  __builtin_amdgcn_global_load_lds(
      (const __attribute__((address_space(1))) unsigned int*)g,
      (__attribute__((address_space(3))) unsigned int*)l, 16, 0, 0);
}

// ---------------- fp32 -> bf16 cast (vectorized) ----------------
__global__ __launch_bounds__(256) void cast_f32_bf16(const float* __restrict__ in,
                                                     unsigned short* __restrict__ out,
                                                     int n) {
  int i = (blockIdx.x * 256 + threadIdx.x) * 4;
  if (i >= n) return;
  f32x4 v = *(const f32x4*)&in[i];
  u16x4 o;
  o[0] = f2bf(v[0]); o[1] = f2bf(v[1]); o[2] = f2bf(v[2]); o[3] = f2bf(v[3]);
  *(u16x4*)&out[i] = o;
}

// ---------------- out += p1 + p2 (split-K reduce) ----------------
__global__ __launch_bounds__(256) void add2f32(float* __restrict__ out,
                                               const float* __restrict__ p1,
                                               const float* __restrict__ p2, int n) {
  int i = (blockIdx.x * 256 + threadIdx.x) * 4;
  if (i >= n) return;
  f32x4 a = *(const f32x4*)&out[i];
  f32x4 b = *(const f32x4*)&p1[i];
  f32x4 c = *(const f32x4*)&p2[i];
  a[0] += b[0] + c[0]; a[1] += b[1] + c[1];
  a[2] += b[2] + c[2]; a[3] += b[3] + c[3];
  *(f32x4*)&out[i] = a;
}

// ---------------- bf16 GEMM: C[M,N] = A[M,K] * B[N,K]^T ----------------
// 128x128 tile, BK=32, 4 waves, double-buffered global_load_lds w=16.
// Chunk-swizzled LDS (rule #21: linear LDS dest, permuted GLOBAL source,
// same XOR on reads): staging lane l loads chunk (l&3)^((l>>2)&3) of its row,
// reads use chunk (lane>>4)^(row&3). 4-lane groups still cover one 64-B
// segment (coalescing unchanged); read conflicts 8-way -> 4-way.
// blockIdx.z selects K-slice [z*KS, min(K,(z+1)*KS)); z=0 -> Cv, z=1/2 -> Cp1/2.
template<int OUT_BF16>
__global__ __launch_bounds__(256) void gemm_bt(const unsigned short* __restrict__ A,
                                               const unsigned short* __restrict__ B,
                                               void* __restrict__ Cv,
                                               float* __restrict__ Cp1,
                                               float* __restrict__ Cp2,
                                               int M, int N, int K, int KS) {
  __shared__ unsigned short As[2][128 * 32];
  __shared__ unsigned short Bs[2][128 * 32];

  const int tid  = threadIdx.x;
  const int lane = tid & 63;
  const int wave = tid >> 6;            // 0..3
  const int wr = (wave >> 1) * 64;
  const int wc = (wave & 1) * 64;
  const int row0 = blockIdx.y * 128;
  const int col0 = blockIdx.x * 128;
  const int l16 = lane & 15;
  const int lkA = ((lane >> 4) ^ (lane & 3)) * 8;   // swizzled read chunk offset
  const int kbeg = blockIdx.z * KS;
  const int kend = (kbeg + KS < K) ? (kbeg + KS) : K;

  // staging: instr t (= wave*2+i) covers LDS rows t*16..t*16+15.
  // lane l -> row t*16 + (l>>2), SWIZZLED chunk ((l&3)^((l>>2)&3))*8
  const int srow = lane >> 2;
  const int scs  = ((lane & 3) ^ ((lane >> 2) & 3)) * 8;

  f32x4 acc[4][4] = {};

  // prologue: fill buffer 0
#pragma unroll
  for (int i = 0; i < 2; ++i) {
    int t = wave * 2 + i;
    int r = t * 16 + srow;
    gload_lds16(&A[(size_t)(row0 + r) * K + kbeg + scs], &As[0][t * 512]);
    gload_lds16(&B[(size_t)(col0 + r) * K + kbeg + scs], &Bs[0][t * 512]);
  }
  __syncthreads();

  int cur = 0;
  for (int k0 = kbeg; k0 < kend; k0 += 32, cur ^= 1) {
    if (k0 + 32 < kend) {
#pragma unroll
      for (int i = 0; i < 2; ++i) {
        int t = wave * 2 + i;
        int r = t * 16 + srow;
        gload_lds16(&A[(size_t)(row0 + r) * K + k0 + 32 + scs], &As[cur ^ 1][t * 512]);
        gload_lds16(&B[(size_t)(col0 + r) * K + k0 + 32 + scs], &Bs[cur ^ 1][t * 512]);
      }
    }

    bf16x8 af[4], bfr[4];
#pragma unroll
    for (int i = 0; i < 4; ++i) af[i]  = *(const bf16x8*)&As[cur][(wr + i * 16 + l16) * 32 + lkA];
#pragma unroll
    for (int i = 0; i < 4; ++i) bfr[i] = *(const bf16x8*)&Bs[cur][(wc + i * 16 + l16) * 32 + lkA];
#pragma unroll
    for (int i = 0; i < 4; ++i)
#pragma unroll
      for (int j = 0; j < 4; ++j)
        acc[i][j] = __builtin_amdgcn_mfma_f32_16x16x32_bf16(af[i], bfr[j], acc[i][j], 0, 0, 0);

    __syncthreads();
  }

  void* outp = (blockIdx.z == 0) ? Cv : (blockIdx.z == 1 ? (void*)Cp1 : (void*)Cp2);

  // epilogue: C/D layout col = lane&15, row = (lane>>4)*4 + r
  const int orow = (lane >> 4) * 4;
#pragma unroll
  for (int i = 0; i < 4; ++i)
#pragma unroll
    for (int j = 0; j < 4; ++j)
#pragma unroll
      for (int r = 0; r < 4; ++r) {
        size_t gr = row0 + wr + i * 16 + orow + r;
        size_t gc = col0 + wc + j * 16 + l16;
        float v = acc[i][j][r];
        if (OUT_BF16) ((unsigned short*)outp)[gr * N + gc] = f2bf(v);
        else          ((float*)outp)[gr * N + gc] = v;
      }
}

// ---------------- causal flash attention (UNCHANGED from round 12) ----------------
#define KS_IDX(r, c) ((((r) * 128) + (c)) ^ (((r) & 7) << 3))
#define VT_IDX(c, t) ((((c) * 64) + (t)) ^ (((((c) ^ ((c) >> 3))) & 7) << 3))
#define PS_IDX(q, c) ((((q) * 64) + (c)) ^ (((((q) & 7) ^ (((q) >> 2) & 3))) << 3))

__global__ __launch_bounds__(256, 2) void attn_kernel(const unsigned short* __restrict__ qkv,
                                                      unsigned short* __restrict__ ctx) {
  __shared__ unsigned short Ks[2][64 * 128];   // K [kv][c], swizzled, dbuf
  __shared__ unsigned short VTs[2][128 * 64];  // V^T [c][kv], swizzled, dbuf
  __shared__ unsigned short Ps[4][16 * 64];    // per-wave P [q][kv], swizzled

  const int tid  = threadIdx.x;
  const int lane = tid & 63;
  const int w    = tid >> 6;
  const int l16  = lane & 15;
  const int lk8  = (lane >> 4) * 8;

  // balanced (h, qb): co-resident blocks (flat, flat+256) have complementary qb.
  const int flat = blockIdx.x + blockIdx.y * 32;
  int h, qb;
  if (flat < 256) { h = flat >> 5; qb = flat & 31; }
  else            { int f2 = flat - 256; h = 8 + (f2 >> 5); qb = 31 - (f2 & 31); }

  const int qrow = qb * 64 + w * 16;

  const unsigned short* Kbase = qkv + 2048 + h * 128;
  const unsigned short* Vbase = qkv + 4096 + h * 128;

  // Q fragments in registers for the whole kv loop
  bf16x8 qf[4];
#pragma unroll
  for (int kk = 0; kk < 4; ++kk)
    qf[kk] = *(const bf16x8*)&qkv[(size_t)(qrow + l16) * 6144 + h * 128 + kk * 32 + lk8];

  f32x4 o[8] = {};
  float m[4], ls[4];
#pragma unroll
  for (int r = 0; r < 4; ++r) { m[r] = -1e30f; ls[r] = 0.f; }

  const float sscale = 0.08838834764831845f * 1.4426950408889634f;  // 1/sqrt(128)*log2e
  const int qg0 = qrow + (lane >> 4) * 4;

  const int t0v = (tid & 15) * 4;
  const int c0v = (tid >> 4) * 8;

  // prologue: stage tile 0 into buffers 0 (visible after iter-0 barrier)
  {
    u32x4 kr[4], vr[4];
#pragma unroll
    for (int it = 0; it < 4; ++it) {
      int idx = it * 256 + tid;
      int row = idx >> 4, c0 = (idx & 15) * 8;
      kr[it] = *(const u32x4*)&Kbase[(size_t)row * 6144 + c0];
    }
#pragma unroll
    for (int r = 0; r < 4; ++r)
      vr[r] = *(const u32x4*)&Vbase[(size_t)(t0v + r) * 6144 + c0v];
#pragma unroll
    for (int it = 0; it < 4; ++it) {
      int idx = it * 256 + tid;
      int row = idx >> 4, c0 = (idx & 15) * 8;
      *(u32x4*)&Ks[0][KS_IDX(row, c0)] = kr[it];
    }
    const unsigned short* p0 = (const unsigned short*)&vr[0];
    const unsigned short* p1 = (const unsigned short*)&vr[1];
    const unsigned short* p2 = (const unsigned short*)&vr[2];
    const unsigned short* p3 = (const unsigned short*)&vr[3];
#pragma unroll
    for (int j = 0; j < 8; ++j) {
      u16x4 wv; wv[0] = p0[j]; wv[1] = p1[j]; wv[2] = p2[j]; wv[3] = p3[j];
      *(u16x4*)&VTs[0][VT_IDX(c0v + j, t0v)] = wv;
    }
  }

  const int nkb = qb + 1;
  for (int kb = 0; kb < nkb; ++kb) {
    const int cur = kb & 1;
    const bool pre = (kb + 1 < nkb);

    // prefetch next K/V tile to regs BEFORE the barrier
    u32x4 kr[4], vr[4];
    if (pre) {
#pragma unroll
      for (int it = 0; it < 4; ++it) {
        int idx = it * 256 + tid;
        int row = idx >> 4, c0 = (idx & 15) * 8;
        kr[it] = *(const u32x4*)&Kbase[(size_t)((kb + 1) * 64 + row) * 6144 + c0];
      }
#pragma unroll
      for (int r = 0; r < 4; ++r)
        vr[r] = *(const u32x4*)&Vbase[(size_t)((kb + 1) * 64 + t0v + r) * 6144 + c0v];
    }

    __syncthreads();

    if (pre) {
#pragma unroll
      for (int it = 0; it < 4; ++it) {
        int idx = it * 256 + tid;
        int row = idx >> 4, c0 = (idx & 15) * 8;
        *(u32x4*)&Ks[cur ^ 1][KS_IDX(row, c0)] = kr[it];
      }
      const unsigned short* p0 = (const unsigned short*)&vr[0];
      const unsigned short* p1 = (const unsigned short*)&vr[1];
      const unsigned short* p2 = (const unsigned short*)&vr[2];
      const unsigned short* p3 = (const unsigned short*)&vr[3];
#pragma unroll
      for (int j = 0; j < 8; ++j) {
        u16x4 wv; wv[0] = p0[j]; wv[1] = p1[j]; wv[2] = p2[j]; wv[3] = p3[j];
        *(u16x4*)&VTs[cur ^ 1][VT_IDX(c0v + j, t0v)] = wv;
      }
    }

    // S = Q K^T (16x64 per wave), K from LDS
    f32x4 s[4] = {};
#pragma unroll
    for (int n = 0; n < 4; ++n)
#pragma unroll
      for (int kk = 0; kk < 4; ++kk) {
        bf16x8 kf = *(const bf16x8*)&Ks[cur][KS_IDX(n * 16 + l16, kk * 32 + lk8)];
        s[n] = __builtin_amdgcn_mfma_f32_16x16x32_bf16(qf[kk], kf, s[n], 0, 0, 0);
      }

    // scale + causal mask + lane-local max
    const bool diag = (kb == qb);
    float pmax[4];
#pragma unroll
    for (int r = 0; r < 4; ++r) pmax[r] = -1e30f;
#pragma unroll
    for (int n = 0; n < 4; ++n) {
      int kg = kb * 64 + n * 16 + l16;
#pragma unroll
      for (int r = 0; r < 4; ++r) {
        float v = s[n][r] * sscale;
        if (diag && kg > qg0 + r) v = -1e30f;
        s[n][r] = v;
        pmax[r] = fmaxf(pmax[r], v);
      }
    }

    // defer-max: only reduce+rescale when some row grew past m+8
    bool need = (pmax[0] > m[0] + 8.f) | (pmax[1] > m[1] + 8.f) |
                (pmax[2] > m[2] + 8.f) | (pmax[3] > m[3] + 8.f);
    if (__ballot(need)) {
#pragma unroll
      for (int d = 1; d < 16; d <<= 1)
#pragma unroll
        for (int r = 0; r < 4; ++r) pmax[r] = fmaxf(pmax[r], __shfl_xor(pmax[r], d));
#pragma unroll
      for (int r = 0; r < 4; ++r) {
        float mn = fmaxf(m[r], pmax[r]);
        float alpha = exp2f(m[r] - mn);
        m[r] = mn;
        ls[r] *= alpha;
#pragma unroll
        for (int n = 0; n < 8; ++n) o[n][r] *= alpha;
      }
    }

    // P = exp2(s - m): bf16 to Ps, lane-local denominator accumulation
#pragma unroll
    for (int n = 0; n < 4; ++n)
#pragma unroll
      for (int r = 0; r < 4; ++r) {
        float p = exp2f(s[n][r] - m[r]);
        ls[r] += p;
        Ps[w][PS_IDX((lane >> 4) * 4 + r, n * 16 + l16)] = f2bf(p);
      }
    asm volatile("s_waitcnt lgkmcnt(0)" ::: "memory");  // wave-private Ps: no barrier

    // O += P V
#pragma unroll
    for (int kk = 0; kk < 2; ++kk) {
      bf16x8 pf = *(const bf16x8*)&Ps[w][PS_IDX(l16, kk * 32 + lk8)];
#pragma unroll
      for (int n = 0; n < 8; ++n) {
        bf16x8 vf = *(const bf16x8*)&VTs[cur][VT_IDX(n * 16 + l16, kk * 32 + lk8)];
        o[n] = __builtin_amdgcn_mfma_f32_16x16x32_bf16(pf, vf, o[n], 0, 0, 0);
      }
    }
  }

  // denominator: one cross-lane reduce at the end
#pragma unroll
  for (int d = 1; d < 16; d <<= 1)
#pragma unroll
    for (int r = 0; r < 4; ++r) ls[r] += __shfl_xor(ls[r], d);

  // epilogue
#pragma unroll
  for (int r = 0; r < 4; ++r) {
    float inv = 1.0f / ls[r];
    size_t gr = qrow + (lane >> 4) * 4 + r;
#pragma unroll
    for (int n = 0; n < 8; ++n)
      ctx[gr * 2048 + h * 128 + n * 16 + l16] = f2bf(o[n][r] * inv);
  }
}

// ---------------- launch ----------------
extern "C" void kernel_launch(void* const* d_in, const int* in_sizes, int n_in,
                              void* d_out, int out_size, void* d_ws, size_t ws_size,
                              hipStream_t stream) {
  const float* x  = (const float*)d_in[0];
  const float* Wa = (const float*)d_in[1];
  const float* Wp = (const float*)d_in[2];
  float* out = (float*)d_out;

  char* ws = (char*)d_ws;
  unsigned short* xb   = (unsigned short*)(ws);                       // 8 MB
  unsigned short* wab  = (unsigned short*)(ws + 8388608);             // 24 MB
  unsigned short* wpb  = (unsigned short*)(ws + 33554432);            // 8 MB
  unsigned short* qkvb = (unsigned short*)(ws + 41943040);            // 24 MB
  unsigned short* ctx  = (unsigned short*)(ws + 67108864);            // 8 MB
  // split-K partials ALIAS dead regions (no new workspace):
  //  p1 over wab  (W_attn bf16 — dead after qkv GEMM)
  //  p2 over qkvb (qkv bf16    — dead after attn)
  float* proj_p1 = (float*)(ws + 8388608);    // 16 MB <= wab's 24 MB
  float* proj_p2 = (float*)(ws + 41943040);   // 16 MB <= qkvb's 24 MB

  cast_f32_bf16<<<4096, 256, 0, stream>>>(x, xb, 2048 * 2048);
  cast_f32_bf16<<<12288, 256, 0, stream>>>(Wa, wab, 6144 * 2048);
  cast_f32_bf16<<<4096, 256, 0, stream>>>(Wp, wpb, 2048 * 2048);

  // qkv = x @ W_attn^T : [2048, 6144]
  gemm_bt<1><<<dim3(48, 16, 1), 256, 0, stream>>>(xb, wab, qkvb, nullptr, nullptr,
                                                  2048, 6144, 2048, 2048);

  // causal multi-head attention -> ctx [2048, 2048] bf16
  attn_kernel<<<dim3(32, 16), 256, 0, stream>>>(qkvb, ctx);

  // out = ctx @ W_proj^T : [2048, 2048] fp32, split-K=3 (768 blocks = 3/CU)
  gemm_bt<0><<<dim3(16, 16, 3), 256, 0, stream>>>(ctx, wpb, out, proj_p1, proj_p2,
                                                  2048, 2048, 2048, 704);
  add2f32<<<4096, 256, 0, stream>>>(out, proj_p1, proj_p2, 2048 * 2048);
}